// Round 10
// baseline (256.828 us; speedup 1.0000x reference)
//
#include <hip/hip_runtime.h>

#define NTH 512

typedef __attribute__((ext_vector_type(8))) short short8;
typedef __attribute__((ext_vector_type(4))) float floatx4;

// ---- bf16 helpers ----
__device__ __forceinline__ short f2bf(float f) {            // RN-even (setup only)
    unsigned u = __float_as_uint(f);
    u += 0x7FFF + ((u >> 16) & 1);
    return (short)(u >> 16);
}
__device__ __forceinline__ short f2bf_trunc(float f) {      // truncate (hot loop)
    return (short)(__float_as_uint(f) >> 16);
}
__device__ __forceinline__ float bf2f(short s) {
    return __uint_as_float(((unsigned)(unsigned short)s) << 16);
}
__device__ __forceinline__ float bf_hi_f(float f) {         // trunc-to-bf16 as float
    return __uint_as_float(__float_as_uint(f) & 0xFFFF0000u);
}

__device__ __forceinline__ float fast_sigmoid(float x) {
    return __builtin_amdgcn_rcpf(1.f + __expf(-x));
}
__device__ __forceinline__ float fast_tanh(float x) {
    return fmaf(-2.f, __builtin_amdgcn_rcpf(__expf(2.f * x) + 1.f), 1.f);
}

// DPP add stage; 0x140,0x141,0x4E,0xB1 together = 16-lane sum broadcast
template<int CTRL>
__device__ __forceinline__ float dpp_add(float v) {
    int o = __builtin_amdgcn_update_dpp(0, __float_as_int(v), CTRL, 0xF, 0xF, true);
    return v + __int_as_float(o);
}

#define MFMA __builtin_amdgcn_mfma_f32_16x16x32_bf16

// ---------------------------------------------------------------------------
// Encoder layer: [32,128] (LDS) @ W[128,128] + bias -> [32,128] (LDS)
// ---------------------------------------------------------------------------
template<bool RELU>
__device__ __forceinline__ void mlp_layer(const float (*in)[132],
                                          const float* __restrict__ W,
                                          const float* __restrict__ bias,
                                          float (*outl)[132], int c, int g) {
    float acc[8];
    #pragma unroll
    for (int i = 0; i < 8; i++) acc[i] = 0.f;
    for (int k = 0; k < 128; k += 4) {
        float w0 = W[(k + 0) * 128 + c];
        float w1 = W[(k + 1) * 128 + c];
        float w2 = W[(k + 2) * 128 + c];
        float w3 = W[(k + 3) * 128 + c];
        #pragma unroll
        for (int i = 0; i < 8; i++) {
            const float4 xv = *(const float4*)&in[g * 8 + i][k];
            acc[i] = fmaf(xv.x, w0, fmaf(xv.y, w1, fmaf(xv.z, w2, fmaf(xv.w, w3, acc[i]))));
        }
    }
    const float bv = bias[c];
    #pragma unroll
    for (int i = 0; i < 8; i++) {
        float v = acc[i] + bv;
        outl[g * 8 + i][c] = RELU ? fmaxf(v, 0.f) : v;
    }
}

// ---------------------------------------------------------------------------
// MFMA phase for one 16-row stream at step k: acc = h_k @ w_hh^T chains,
// dacc = decoder. Reads the stream's planes (chosen buf).
// ---------------------------------------------------------------------------
__device__ __forceinline__ void mfma_phase(const short (*hi)[136], const short (*lo)[136],
                                           int l15, int quad,
                                           const short8 (&wbh)[3][4], const short8 (&wbl)[3][4],
                                           const short8 (&dwh)[4], const short8 (&dwl)[4],
                                           floatx4 (&acc)[3], floatx4& dacc,
                                           bool do_gru, bool do_dec) {
    short8 ah[4], al[4];
    #pragma unroll
    for (int kt = 0; kt < 4; kt++) {
        const int kb = kt * 32 + quad * 8;
        ah[kt] = *(const short8*)&hi[l15][kb];
        al[kt] = *(const short8*)&lo[l15][kb];
    }
    dacc = (floatx4){0.f, 0.f, 0.f, 0.f};
    if (do_dec) {
        #pragma unroll
        for (int kt = 0; kt < 4; kt++) {
            dacc = MFMA(ah[kt], dwh[kt], dacc, 0, 0, 0);
            dacc = MFMA(ah[kt], dwl[kt], dacc, 0, 0, 0);
        }
    }
    if (do_gru) {
        #pragma unroll
        for (int g = 0; g < 3; g++) acc[g] = (floatx4){0.f, 0.f, 0.f, 0.f};
        #pragma unroll
        for (int kt = 0; kt < 4; kt++)
            #pragma unroll
            for (int g = 0; g < 3; g++) {
                acc[g] = MFMA(ah[kt], wbh[g][kt], acc[g], 0, 0, 0);
                acc[g] = MFMA(ah[kt], wbl[g][kt], acc[g], 0, 0, 0);
                acc[g] = MFMA(al[kt], wbh[g][kt], acc[g], 0, 0, 0);
            }
    }
}

// ---------------------------------------------------------------------------
// Gates phase for one stream at step k: DPP-reduce dacc -> xp, write out col k,
// gates -> h_{k+1} into the stream's next-buf planes.
// ---------------------------------------------------------------------------
__device__ __forceinline__ void gates_phase(int k, int srow,
                                            short (*hi_n)[136], short (*lo_n)[136],
                                            int l15, int quad, int jcol, int w,
                                            floatx4 (&acc)[3], floatx4& dacc, float (&hold)[4],
                                            float wihc0, float bs_r, float wihc1, float bs_z,
                                            float wihc2, float bih_n, float bhh_n,
                                            float db0r, float dw1r, float db1r,
                                            float (*outb)[52]) {
    float xp[4];
    #pragma unroll
    for (int reg = 0; reg < 4; reg++) {
        float v = fmaxf(dacc[reg] + db0r, 0.f) * dw1r;
        v = dpp_add<0x140>(v);
        v = dpp_add<0x141>(v);
        v = dpp_add<0x4E>(v);
        v = dpp_add<0xB1>(v);
        xp[reg] = (k == 0) ? 0.f : (v + db1r);
    }
    if (k > 0 && w == 0 && l15 == 0) {
        #pragma unroll
        for (int reg = 0; reg < 4; reg++)
            outb[srow + quad * 4 + reg][k] = xp[reg];
    }
    if (k < 49) {
        #pragma unroll
        for (int reg = 0; reg < 4; reg++) {
            const int r = quad * 4 + reg;
            const float xpv = xp[reg];
            float gr  = fmaf(xpv, wihc0, acc[0][reg] + bs_r);
            float gz  = fmaf(xpv, wihc1, acc[1][reg] + bs_z);
            float ghn = acc[2][reg] + bhh_n;
            float gxn = fmaf(xpv, wihc2, bih_n);
            float rg = fast_sigmoid(gr);
            float zg = fast_sigmoid(gz);
            float ng = fast_tanh(fmaf(rg, ghn, gxn));
            const float hn = fmaf(zg, hold[reg] - ng, ng);
            hold[reg] = hn;
            hi_n[r][jcol] = f2bf_trunc(hn);
            lo_n[r][jcol] = f2bf_trunc(hn - bf_hi_f(hn));
        }
    }
}

// ---------------------------------------------------------------------------
// Fused encoder + two-stream pipelined GRU (bf16x3 MFMA) + decoder.
// Streams = row halves (0-15, 16-31), offset half a step so every
// inter-barrier interval runs MFMA(one stream) || gates(other stream).
// ---------------------------------------------------------------------------
__global__ __launch_bounds__(NTH, 1) __attribute__((amdgpu_waves_per_eu(2)))
void gru_fused_kernel(const float* __restrict__ x,
                      const float* __restrict__ ew0, const float* __restrict__ eb0,
                      const float* __restrict__ ew1, const float* __restrict__ eb1,
                      const float* __restrict__ ew2, const float* __restrict__ eb2,
                      const float* __restrict__ w_ih, const float* __restrict__ w_hh,
                      const float* __restrict__ b_ih, const float* __restrict__ b_hh,
                      const float* __restrict__ dw0, const float* __restrict__ db0,
                      const float* __restrict__ dw1, const float* __restrict__ db1,
                      float* __restrict__ out) {
    __shared__ float hA[32][132];                        // encoder staging
    __shared__ float smemB[32 * 132];                    // encoder ping buffer
    __shared__ __align__(16) short h_hi[2][2][16][136];  // [stream][buf][row][col]
    __shared__ __align__(16) short h_lo[2][2][16][136];
    __shared__ float outb[32][52];

    const int tid  = threadIdx.x;
    const int b0   = blockIdx.x * 32;
    const int lane = tid & 63;
    const int w    = tid >> 6;     // wave 0..7
    const int quad = lane >> 4;
    const int l15  = lane & 15;
    const int jcol = w * 16 + l15; // this lane's hidden col (per gate)

    // ---------------- encoder: x -> hA ----------------
    {
        const int c = tid & 127;
        const int g = tid >> 7;    // 0..3, 8 rows each
        float acc[8];
        #pragma unroll
        for (int i = 0; i < 8; i++) acc[i] = 0.f;
        for (int k = 0; k < 256; k += 4) {
            float w0 = ew0[(k + 0) * 128 + c];
            float w1 = ew0[(k + 1) * 128 + c];
            float w2 = ew0[(k + 2) * 128 + c];
            float w3 = ew0[(k + 3) * 128 + c];
            #pragma unroll
            for (int i = 0; i < 8; i++) {
                const float4 xv = *(const float4*)(x + (size_t)(b0 + g * 8 + i) * 256 + k);
                acc[i] = fmaf(xv.x, w0, fmaf(xv.y, w1, fmaf(xv.z, w2, fmaf(xv.w, w3, acc[i]))));
            }
        }
        float bv = eb0[c];
        #pragma unroll
        for (int i = 0; i < 8; i++) hA[g * 8 + i][c] = fmaxf(acc[i] + bv, 0.f);
        __syncthreads();
        mlp_layer<true>(hA, ew1, eb1, (float(*)[132])smemB, c, g);
        __syncthreads();
        mlp_layer<false>((float(*)[132])smemB, ew2, eb2, hA, c, g);
        __syncthreads();
    }

    // ---------------- persistent register weights ----------------
    short8 wbh[3][4], wbl[3][4];
    #pragma unroll
    for (int g = 0; g < 3; g++) {
        const float* wrow = w_hh + (g * 128 + jcol) * 128;
        #pragma unroll
        for (int kt = 0; kt < 4; kt++) {
            const int kb = kt * 32 + quad * 8;
            const float4 f0 = *(const float4*)(wrow + kb);
            const float4 f1 = *(const float4*)(wrow + kb + 4);
            float fv[8] = {f0.x, f0.y, f0.z, f0.w, f1.x, f1.y, f1.z, f1.w};
            short8 hi, lo;
            #pragma unroll
            for (int e = 0; e < 8; e++) {
                short h = f2bf(fv[e]);
                hi[e] = h;
                lo[e] = f2bf_trunc(fv[e] - bf2f(h));
            }
            wbh[g][kt] = hi;
            wbl[g][kt] = lo;
        }
    }
    short8 dwh[4], dwl[4];
    #pragma unroll
    for (int kt = 0; kt < 4; kt++) {
        short8 hi, lo;
        #pragma unroll
        for (int e = 0; e < 8; e++) {
            float f = dw0[(kt * 32 + quad * 8 + e) * 16 + l15];
            short h = f2bf(f);
            hi[e] = h;
            lo[e] = f2bf_trunc(f - bf2f(h));
        }
        dwh[kt] = hi;
        dwl[kt] = lo;
    }
    // gate constants: folded biases for r,z; split for n
    float wihc0 = w_ih[jcol],       bs_r  = b_ih[jcol] + b_hh[jcol];
    float wihc1 = w_ih[128 + jcol], bs_z  = b_ih[128 + jcol] + b_hh[128 + jcol];
    float wihc2 = w_ih[256 + jcol], bih_n = b_ih[256 + jcol], bhh_n = b_hh[256 + jcol];
    const float db0r = db0[l15];
    const float dw1r = dw1[l15];
    const float db1r = db1[0];

    // ---------------- init planes[s][0] + lane-private fp32 h ----------------
    for (int i = tid; i < 32 * 128; i += NTH) {
        const int b = i >> 7, j = i & 127;
        const float f = hA[b][j];
        h_hi[b >> 4][0][b & 15][j] = f2bf_trunc(f);
        h_lo[b >> 4][0][b & 15][j] = f2bf_trunc(f - bf_hi_f(f));
    }
    if (tid < 32) outb[tid][0] = 0.f;
    float hold0[4], hold1[4];
    #pragma unroll
    for (int reg = 0; reg < 4; reg++) {
        hold0[reg] = hA[quad * 4 + reg][jcol];
        hold1[reg] = hA[16 + quad * 4 + reg][jcol];
    }
    __syncthreads();

    // ---------------- pipelined 2-stream loop ----------------
    floatx4 acc0[3], acc1[3], dacc0, dacc1;

    // prologue (interval 0): MFMA(s0, k=0); no gates yet
    mfma_phase(h_hi[0][0], h_lo[0][0], l15, quad, wbh, wbl, dwh, dwl,
               acc0, dacc0, true, false);
    __syncthreads();

    for (int k = 0; k < 50; k++) {
        const int cur = k & 1, nxt = cur ^ 1;

        // interval 2k+1: MFMA(s1, k) || gates(s0, k)
        mfma_phase(h_hi[1][cur], h_lo[1][cur], l15, quad, wbh, wbl, dwh, dwl,
                   acc1, dacc1, k < 49, k > 0);
        gates_phase(k, 0, h_hi[0][nxt], h_lo[0][nxt], l15, quad, jcol, w,
                    acc0, dacc0, hold0,
                    wihc0, bs_r, wihc1, bs_z, wihc2, bih_n, bhh_n,
                    db0r, dw1r, db1r, outb);
        __syncthreads();

        // interval 2k+2: MFMA(s0, k+1) || gates(s1, k)
        if (k < 49)
            mfma_phase(h_hi[0][nxt], h_lo[0][nxt], l15, quad, wbh, wbl, dwh, dwl,
                       acc0, dacc0, k + 1 < 49, true);
        gates_phase(k, 16, h_hi[1][nxt], h_lo[1][nxt], l15, quad, jcol, w,
                    acc1, dacc1, hold1,
                    wihc0, bs_r, wihc1, bs_z, wihc2, bih_n, bhh_n,
                    db0r, dw1r, db1r, outb);
        __syncthreads();
    }

    // coalesced output write: [32 rows][50 cols], col 0 = 0
    for (int e = tid; e < 32 * 50; e += NTH) {
        const int b = e / 50;
        const int t = e - b * 50;
        out[(size_t)b0 * 50 + e] = outb[b][t];
    }
}

// ---------------------------------------------------------------------------
extern "C" void kernel_launch(void* const* d_in, const int* in_sizes, int n_in,
                              void* d_out, int out_size, void* d_ws, size_t ws_size,
                              hipStream_t stream) {
    const float* x   = (const float*)d_in[0];
    const float* ew0 = (const float*)d_in[1];
    const float* eb0 = (const float*)d_in[2];
    const float* ew1 = (const float*)d_in[3];
    const float* eb1 = (const float*)d_in[4];
    const float* ew2 = (const float*)d_in[5];
    const float* eb2 = (const float*)d_in[6];
    const float* wih = (const float*)d_in[7];
    const float* whh = (const float*)d_in[8];
    const float* bih = (const float*)d_in[9];
    const float* bhh = (const float*)d_in[10];
    const float* dw0 = (const float*)d_in[11];
    const float* db0 = (const float*)d_in[12];
    const float* dw1 = (const float*)d_in[13];
    const float* db1 = (const float*)d_in[14];
    float* out = (float*)d_out;

    gru_fused_kernel<<<256, NTH, 0, stream>>>(
        x, ew0, eb0, ew1, eb1, ew2, eb2, wih, whh, bih, bhh,
        dw0, db0, dw1, db1, out);
}

// Round 11
// 242.217 us; speedup vs baseline: 1.0603x; 1.0603x over previous
//
#include <hip/hip_runtime.h>

#define NTH 512

typedef _Float16 half8 __attribute__((ext_vector_type(8)));
typedef __attribute__((ext_vector_type(4))) float floatx4;

__device__ __forceinline__ float fast_sigmoid(float x) {
    return __builtin_amdgcn_rcpf(1.f + __expf(-x));
}
__device__ __forceinline__ float fast_tanh(float x) {
    return fmaf(-2.f, __builtin_amdgcn_rcpf(__expf(2.f * x) + 1.f), 1.f);
}

// DPP add stage; 0x140,0x141,0x4E,0xB1 together = 16-lane sum broadcast
template<int CTRL>
__device__ __forceinline__ float dpp_add(float v) {
    int o = __builtin_amdgcn_update_dpp(0, __float_as_int(v), CTRL, 0xF, 0xF, true);
    return v + __int_as_float(o);
}

#define MFMA16 __builtin_amdgcn_mfma_f32_16x16x32_f16

// ---------------------------------------------------------------------------
// Encoder layer: [32,128] (LDS) @ W[128,128] + bias -> [32,128] (LDS)
// ---------------------------------------------------------------------------
template<bool RELU>
__device__ __forceinline__ void mlp_layer(const float (*in)[132],
                                          const float* __restrict__ W,
                                          const float* __restrict__ bias,
                                          float (*outl)[132], int c, int g) {
    float acc[8];
    #pragma unroll
    for (int i = 0; i < 8; i++) acc[i] = 0.f;
    for (int k = 0; k < 128; k += 4) {
        float w0 = W[(k + 0) * 128 + c];
        float w1 = W[(k + 1) * 128 + c];
        float w2 = W[(k + 2) * 128 + c];
        float w3 = W[(k + 3) * 128 + c];
        #pragma unroll
        for (int i = 0; i < 8; i++) {
            const float4 xv = *(const float4*)&in[g * 8 + i][k];
            acc[i] = fmaf(xv.x, w0, fmaf(xv.y, w1, fmaf(xv.z, w2, fmaf(xv.w, w3, acc[i]))));
        }
    }
    const float bv = bias[c];
    #pragma unroll
    for (int i = 0; i < 8; i++) {
        float v = acc[i] + bv;
        outl[g * 8 + i][c] = RELU ? fmaxf(v, 0.f) : v;
    }
}

// ---------------------------------------------------------------------------
// Fused encoder + 50-iter GRU (f16x2 MFMA: h split hi/lo f16 -> h exact,
// W single f16) + per-wave decoder (DPP reduce). 32 rows/block, 8 waves;
// wave w owns gate cols {g*128 + w*16 + l15}. One barrier per step.
// GRU: gh = h_hi @ W16 + h_lo @ W16  (2 passes; error = W quantization only)
// ---------------------------------------------------------------------------
__global__ __launch_bounds__(NTH, 1) __attribute__((amdgpu_waves_per_eu(2)))
void gru_fused_kernel(const float* __restrict__ x,
                      const float* __restrict__ ew0, const float* __restrict__ eb0,
                      const float* __restrict__ ew1, const float* __restrict__ eb1,
                      const float* __restrict__ ew2, const float* __restrict__ eb2,
                      const float* __restrict__ w_ih, const float* __restrict__ w_hh,
                      const float* __restrict__ b_ih, const float* __restrict__ b_hh,
                      const float* __restrict__ dw0, const float* __restrict__ db0,
                      const float* __restrict__ dw1, const float* __restrict__ db1,
                      float* __restrict__ out) {
    __shared__ float hA[32][132];                        // encoder staging
    __shared__ float smemB[32 * 132];                    // encoder ping buffer
    __shared__ __align__(16) _Float16 h_hi[2][32][136];  // f16 hi planes (dbuf)
    __shared__ __align__(16) _Float16 h_lo[2][32][136];  // f16 lo planes (dbuf)
    __shared__ float outb[32][52];

    const int tid  = threadIdx.x;
    const int b0   = blockIdx.x * 32;
    const int lane = tid & 63;
    const int w    = tid >> 6;     // wave 0..7
    const int quad = lane >> 4;
    const int l15  = lane & 15;
    const int jcol = w * 16 + l15; // this lane's hidden col (per gate)

    // ---------------- encoder: x -> hA ----------------
    {
        const int c = tid & 127;
        const int g = tid >> 7;    // 0..3, 8 rows each
        float acc[8];
        #pragma unroll
        for (int i = 0; i < 8; i++) acc[i] = 0.f;
        for (int k = 0; k < 256; k += 4) {
            float w0 = ew0[(k + 0) * 128 + c];
            float w1 = ew0[(k + 1) * 128 + c];
            float w2 = ew0[(k + 2) * 128 + c];
            float w3 = ew0[(k + 3) * 128 + c];
            #pragma unroll
            for (int i = 0; i < 8; i++) {
                const float4 xv = *(const float4*)(x + (size_t)(b0 + g * 8 + i) * 256 + k);
                acc[i] = fmaf(xv.x, w0, fmaf(xv.y, w1, fmaf(xv.z, w2, fmaf(xv.w, w3, acc[i]))));
            }
        }
        float bv = eb0[c];
        #pragma unroll
        for (int i = 0; i < 8; i++) hA[g * 8 + i][c] = fmaxf(acc[i] + bv, 0.f);
        __syncthreads();
        mlp_layer<true>(hA, ew1, eb1, (float(*)[132])smemB, c, g);
        __syncthreads();
        mlp_layer<false>((float(*)[132])smemB, ew2, eb2, hA, c, g);
        __syncthreads();
    }

    // ---------------- persistent register weights (single f16 plane) -------
    half8 wb16[3][4];
    #pragma unroll
    for (int g = 0; g < 3; g++) {
        const float* wrow = w_hh + (g * 128 + jcol) * 128;
        #pragma unroll
        for (int kt = 0; kt < 4; kt++) {
            const int kb = kt * 32 + quad * 8;
            half8 hv;
            #pragma unroll
            for (int e = 0; e < 8; e++) hv[e] = (_Float16)wrow[kb + e];
            wb16[g][kt] = hv;
        }
    }
    half8 dw16[4];
    #pragma unroll
    for (int kt = 0; kt < 4; kt++) {
        half8 hv;
        #pragma unroll
        for (int e = 0; e < 8; e++)
            hv[e] = (_Float16)dw0[(kt * 32 + quad * 8 + e) * 16 + l15];
        dw16[kt] = hv;
    }
    // gate constants: folded biases for r,z; split for n
    float wihc0 = w_ih[jcol],       bs_r  = b_ih[jcol] + b_hh[jcol];
    float wihc1 = w_ih[128 + jcol], bs_z  = b_ih[128 + jcol] + b_hh[128 + jcol];
    float wihc2 = w_ih[256 + jcol], bih_n = b_ih[256 + jcol], bhh_n = b_hh[256 + jcol];
    const float db0r = db0[l15];
    const float dw1r = dw1[l15];
    const float db1r = db1[0];

    // ---------------- init planes[0] + lane-private fp32 h ----------------
    for (int i = tid; i < 32 * 128; i += NTH) {
        const int b = i >> 7, j = i & 127;
        const float f = hA[b][j];
        const _Float16 hi = (_Float16)f;
        h_hi[0][b][j] = hi;
        h_lo[0][b][j] = (_Float16)(f - (float)hi);
    }
    if (tid < 32) outb[tid][0] = 0.f;
    float hold[8];
    #pragma unroll
    for (int mt = 0; mt < 2; mt++)
        #pragma unroll
        for (int reg = 0; reg < 4; reg++)
            hold[mt * 4 + reg] = hA[mt * 16 + quad * 4 + reg][jcol];
    __syncthreads();

    // ---------------- 50 iterations: dec(h_t) -> out[t]; gates -> h_{t+1} ---
    for (int t = 0; t <= 49; t++) {
        const int cur = t & 1, nxt = cur ^ 1;

        // all A-frags upfront (16 b128; single drain)
        half8 ah[2][4], al[2][4];
        #pragma unroll
        for (int mt = 0; mt < 2; mt++)
            #pragma unroll
            for (int kt = 0; kt < 4; kt++) {
                const int kb = kt * 32 + quad * 8;
                ah[mt][kt] = *(const half8*)&h_hi[cur][mt * 16 + l15][kb];
                al[mt][kt] = *(const half8*)&h_lo[cur][mt * 16 + l15][kb];
            }

        // decoder (2-pass: h exact, dw f16): dacc ready early for the reduce
        floatx4 dacc[2];
        dacc[0] = (floatx4){0.f, 0.f, 0.f, 0.f};
        dacc[1] = (floatx4){0.f, 0.f, 0.f, 0.f};
        #pragma unroll
        for (int kt = 0; kt < 4; kt++) {
            dacc[0] = MFMA16(ah[0][kt], dw16[kt], dacc[0], 0, 0, 0);
            dacc[0] = MFMA16(al[0][kt], dw16[kt], dacc[0], 0, 0, 0);
            dacc[1] = MFMA16(ah[1][kt], dw16[kt], dacc[1], 0, 0, 0);
            dacc[1] = MFMA16(al[1][kt], dw16[kt], dacc[1], 0, 0, 0);
        }

        // GRU MFMAs (2-pass f16: h_hi + h_lo against single W16)
        floatx4 acc[2][3];
        #pragma unroll
        for (int mt = 0; mt < 2; mt++)
            #pragma unroll
            for (int g = 0; g < 3; g++) acc[mt][g] = (floatx4){0.f, 0.f, 0.f, 0.f};
        #pragma unroll
        for (int kt = 0; kt < 4; kt++) {
            #pragma unroll
            for (int g = 0; g < 3; g++) {
                acc[0][g] = MFMA16(ah[0][kt], wb16[g][kt], acc[0][g], 0, 0, 0);
                acc[0][g] = MFMA16(al[0][kt], wb16[g][kt], acc[0][g], 0, 0, 0);
                acc[1][g] = MFMA16(ah[1][kt], wb16[g][kt], acc[1][g], 0, 0, 0);
                acc[1][g] = MFMA16(al[1][kt], wb16[g][kt], acc[1][g], 0, 0, 0);
            }
        }

        // decoder reduce via DPP (16-lane sum, broadcast)
        float xp[8];
        #pragma unroll
        for (int mt = 0; mt < 2; mt++)
            #pragma unroll
            for (int reg = 0; reg < 4; reg++) {
                float v = fmaxf(dacc[mt][reg] + db0r, 0.f) * dw1r;
                v = dpp_add<0x140>(v);   // row_mirror
                v = dpp_add<0x141>(v);   // row_half_mirror
                v = dpp_add<0x4E>(v);    // quad_perm xor2
                v = dpp_add<0xB1>(v);    // quad_perm xor1
                xp[mt * 4 + reg] = (t == 0) ? 0.f : (v + db1r);
            }
        if (t > 0 && w == 0 && l15 == 0) {
            #pragma unroll
            for (int mt = 0; mt < 2; mt++)
                #pragma unroll
                for (int reg = 0; reg < 4; reg++)
                    outb[mt * 16 + quad * 4 + reg][t] = xp[mt * 4 + reg];
        }

        // gates -> h_{t+1} into planes[nxt]
        if (t < 49) {
            #pragma unroll
            for (int mt = 0; mt < 2; mt++) {
                #pragma unroll
                for (int reg = 0; reg < 4; reg++) {
                    const int b = mt * 16 + quad * 4 + reg;
                    const float xpv = xp[mt * 4 + reg];
                    float gr  = fmaf(xpv, wihc0, acc[mt][0][reg] + bs_r);
                    float gz  = fmaf(xpv, wihc1, acc[mt][1][reg] + bs_z);
                    float ghn = acc[mt][2][reg] + bhh_n;
                    float gxn = fmaf(xpv, wihc2, bih_n);
                    float rg = fast_sigmoid(gr);
                    float zg = fast_sigmoid(gz);
                    float ng = fast_tanh(fmaf(rg, ghn, gxn));
                    const float hn = fmaf(zg, hold[mt * 4 + reg] - ng, ng);
                    hold[mt * 4 + reg] = hn;
                    const _Float16 hs = (_Float16)hn;
                    h_hi[nxt][b][jcol] = hs;
                    h_lo[nxt][b][jcol] = (_Float16)(hn - (float)hs);
                }
            }
        }
        __syncthreads();   // planes[nxt] complete; outb[t] visible
    }

    // coalesced output write: [32 rows][50 cols], col 0 = 0
    for (int e = tid; e < 32 * 50; e += NTH) {
        const int b = e / 50;
        const int t = e - b * 50;
        out[(size_t)b0 * 50 + e] = outb[b][t];
    }
}

// ---------------------------------------------------------------------------
extern "C" void kernel_launch(void* const* d_in, const int* in_sizes, int n_in,
                              void* d_out, int out_size, void* d_ws, size_t ws_size,
                              hipStream_t stream) {
    const float* x   = (const float*)d_in[0];
    const float* ew0 = (const float*)d_in[1];
    const float* eb0 = (const float*)d_in[2];
    const float* ew1 = (const float*)d_in[3];
    const float* eb1 = (const float*)d_in[4];
    const float* ew2 = (const float*)d_in[5];
    const float* eb2 = (const float*)d_in[6];
    const float* wih = (const float*)d_in[7];
    const float* whh = (const float*)d_in[8];
    const float* bih = (const float*)d_in[9];
    const float* bhh = (const float*)d_in[10];
    const float* dw0 = (const float*)d_in[11];
    const float* db0 = (const float*)d_in[12];
    const float* dw1 = (const float*)d_in[13];
    const float* db1 = (const float*)d_in[14];
    float* out = (float*)d_out;

    gru_fused_kernel<<<256, NTH, 0, stream>>>(
        x, ew0, eb0, ew1, eb1, ew2, eb2, wih, whh, bih, bhh,
        dw0, db0, dw1, db1, out);
}

// Round 12
// 210.677 us; speedup vs baseline: 1.2191x; 1.1497x over previous
//
#include <hip/hip_runtime.h>

#define NTH 512

typedef _Float16 half8 __attribute__((ext_vector_type(8)));
typedef __attribute__((ext_vector_type(4))) float floatx4;

__device__ __forceinline__ float fast_sigmoid(float x) {
    return __builtin_amdgcn_rcpf(1.f + __expf(-x));
}
__device__ __forceinline__ float fast_tanh(float x) {
    return fmaf(-2.f, __builtin_amdgcn_rcpf(__expf(2.f * x) + 1.f), 1.f);
}

// DPP add stage; 0x140,0x141,0x4E,0xB1 together = 16-lane sum broadcast
template<int CTRL>
__device__ __forceinline__ float dpp_add(float v) {
    int o = __builtin_amdgcn_update_dpp(0, __float_as_int(v), CTRL, 0xF, 0xF, true);
    return v + __int_as_float(o);
}

#define MFMA16 __builtin_amdgcn_mfma_f32_16x16x32_f16

// ---------------------------------------------------------------------------
// Encoder layer: [32,128] (LDS) @ W[128,128] + bias -> [32,128] (LDS)
// ---------------------------------------------------------------------------
template<bool RELU>
__device__ __forceinline__ void mlp_layer(const float (*in)[132],
                                          const float* __restrict__ W,
                                          const float* __restrict__ bias,
                                          float (*outl)[132], int c, int g) {
    float acc[8];
    #pragma unroll
    for (int i = 0; i < 8; i++) acc[i] = 0.f;
    for (int k = 0; k < 128; k += 4) {
        float w0 = W[(k + 0) * 128 + c];
        float w1 = W[(k + 1) * 128 + c];
        float w2 = W[(k + 2) * 128 + c];
        float w3 = W[(k + 3) * 128 + c];
        #pragma unroll
        for (int i = 0; i < 8; i++) {
            const float4 xv = *(const float4*)&in[g * 8 + i][k];
            acc[i] = fmaf(xv.x, w0, fmaf(xv.y, w1, fmaf(xv.z, w2, fmaf(xv.w, w3, acc[i]))));
        }
    }
    const float bv = bias[c];
    #pragma unroll
    for (int i = 0; i < 8; i++) {
        float v = acc[i] + bv;
        outl[g * 8 + i][c] = RELU ? fmaxf(v, 0.f) : v;
    }
}

// ---------------------------------------------------------------------------
// Fused encoder + 50-iter GRU (single-pass f16 MFMA; h state fp32 in regs,
// f16 only inside the matmul) + per-wave decoder (DPP reduce).
// 32 rows/block, 8 waves; wave w owns gate cols {g*128 + w*16 + l15}.
// One barrier per step.
// ---------------------------------------------------------------------------
__global__ __launch_bounds__(NTH, 1) __attribute__((amdgpu_waves_per_eu(2)))
void gru_fused_kernel(const float* __restrict__ x,
                      const float* __restrict__ ew0, const float* __restrict__ eb0,
                      const float* __restrict__ ew1, const float* __restrict__ eb1,
                      const float* __restrict__ ew2, const float* __restrict__ eb2,
                      const float* __restrict__ w_ih, const float* __restrict__ w_hh,
                      const float* __restrict__ b_ih, const float* __restrict__ b_hh,
                      const float* __restrict__ dw0, const float* __restrict__ db0,
                      const float* __restrict__ dw1, const float* __restrict__ db1,
                      float* __restrict__ out) {
    __shared__ float hA[32][132];                        // encoder staging
    __shared__ float smemB[32 * 132];                    // encoder ping buffer
    __shared__ __align__(16) _Float16 h16[2][32][136];   // f16 h planes (dbuf)
    __shared__ float outb[32][52];

    const int tid  = threadIdx.x;
    const int b0   = blockIdx.x * 32;
    const int lane = tid & 63;
    const int w    = tid >> 6;     // wave 0..7
    const int quad = lane >> 4;
    const int l15  = lane & 15;
    const int jcol = w * 16 + l15; // this lane's hidden col (per gate)

    // ---------------- encoder: x -> hA ----------------
    {
        const int c = tid & 127;
        const int g = tid >> 7;    // 0..3, 8 rows each
        float acc[8];
        #pragma unroll
        for (int i = 0; i < 8; i++) acc[i] = 0.f;
        for (int k = 0; k < 256; k += 4) {
            float w0 = ew0[(k + 0) * 128 + c];
            float w1 = ew0[(k + 1) * 128 + c];
            float w2 = ew0[(k + 2) * 128 + c];
            float w3 = ew0[(k + 3) * 128 + c];
            #pragma unroll
            for (int i = 0; i < 8; i++) {
                const float4 xv = *(const float4*)(x + (size_t)(b0 + g * 8 + i) * 256 + k);
                acc[i] = fmaf(xv.x, w0, fmaf(xv.y, w1, fmaf(xv.z, w2, fmaf(xv.w, w3, acc[i]))));
            }
        }
        float bv = eb0[c];
        #pragma unroll
        for (int i = 0; i < 8; i++) hA[g * 8 + i][c] = fmaxf(acc[i] + bv, 0.f);
        __syncthreads();
        mlp_layer<true>(hA, ew1, eb1, (float(*)[132])smemB, c, g);
        __syncthreads();
        mlp_layer<false>((float(*)[132])smemB, ew2, eb2, hA, c, g);
        __syncthreads();
    }

    // ---------------- persistent register weights (single f16 plane) -------
    half8 wb16[3][4];
    #pragma unroll
    for (int g = 0; g < 3; g++) {
        const float* wrow = w_hh + (g * 128 + jcol) * 128;
        #pragma unroll
        for (int kt = 0; kt < 4; kt++) {
            const int kb = kt * 32 + quad * 8;
            half8 hv;
            #pragma unroll
            for (int e = 0; e < 8; e++) hv[e] = (_Float16)wrow[kb + e];
            wb16[g][kt] = hv;
        }
    }
    half8 dw16[4];
    #pragma unroll
    for (int kt = 0; kt < 4; kt++) {
        half8 hv;
        #pragma unroll
        for (int e = 0; e < 8; e++)
            hv[e] = (_Float16)dw0[(kt * 32 + quad * 8 + e) * 16 + l15];
        dw16[kt] = hv;
    }
    // gate constants: folded biases for r,z; split for n
    float wihc0 = w_ih[jcol],       bs_r  = b_ih[jcol] + b_hh[jcol];
    float wihc1 = w_ih[128 + jcol], bs_z  = b_ih[128 + jcol] + b_hh[128 + jcol];
    float wihc2 = w_ih[256 + jcol], bih_n = b_ih[256 + jcol], bhh_n = b_hh[256 + jcol];
    const float db0r = db0[l15];
    const float dw1r = dw1[l15];
    const float db1r = db1[0];

    // ---------------- init planes[0] + lane-private fp32 h ----------------
    for (int i = tid; i < 32 * 128; i += NTH) {
        const int b = i >> 7, j = i & 127;
        h16[0][b][j] = (_Float16)hA[b][j];
    }
    if (tid < 32) outb[tid][0] = 0.f;
    float hold[8];
    #pragma unroll
    for (int mt = 0; mt < 2; mt++)
        #pragma unroll
        for (int reg = 0; reg < 4; reg++)
            hold[mt * 4 + reg] = hA[mt * 16 + quad * 4 + reg][jcol];
    __syncthreads();

    // ---------------- 50 iterations: dec(h_t) -> out[t]; gates -> h_{t+1} ---
    for (int t = 0; t <= 49; t++) {
        const int cur = t & 1, nxt = cur ^ 1;

        // A-frags upfront (8 b128; single drain)
        half8 ah[2][4];
        #pragma unroll
        for (int mt = 0; mt < 2; mt++)
            #pragma unroll
            for (int kt = 0; kt < 4; kt++) {
                const int kb = kt * 32 + quad * 8;
                ah[mt][kt] = *(const half8*)&h16[cur][mt * 16 + l15][kb];
            }

        // decoder (single pass): dacc ready early for the reduce
        floatx4 dacc[2];
        dacc[0] = (floatx4){0.f, 0.f, 0.f, 0.f};
        dacc[1] = (floatx4){0.f, 0.f, 0.f, 0.f};
        #pragma unroll
        for (int kt = 0; kt < 4; kt++) {
            dacc[0] = MFMA16(ah[0][kt], dw16[kt], dacc[0], 0, 0, 0);
            dacc[1] = MFMA16(ah[1][kt], dw16[kt], dacc[1], 0, 0, 0);
        }

        // GRU MFMAs (single pass f16)
        floatx4 acc[2][3];
        #pragma unroll
        for (int mt = 0; mt < 2; mt++)
            #pragma unroll
            for (int g = 0; g < 3; g++) acc[mt][g] = (floatx4){0.f, 0.f, 0.f, 0.f};
        #pragma unroll
        for (int kt = 0; kt < 4; kt++) {
            #pragma unroll
            for (int g = 0; g < 3; g++) {
                acc[0][g] = MFMA16(ah[0][kt], wb16[g][kt], acc[0][g], 0, 0, 0);
                acc[1][g] = MFMA16(ah[1][kt], wb16[g][kt], acc[1][g], 0, 0, 0);
            }
        }

        // decoder reduce via DPP (16-lane sum, broadcast)
        float xp[8];
        #pragma unroll
        for (int mt = 0; mt < 2; mt++)
            #pragma unroll
            for (int reg = 0; reg < 4; reg++) {
                float v = fmaxf(dacc[mt][reg] + db0r, 0.f) * dw1r;
                v = dpp_add<0x140>(v);   // row_mirror
                v = dpp_add<0x141>(v);   // row_half_mirror
                v = dpp_add<0x4E>(v);    // quad_perm xor2
                v = dpp_add<0xB1>(v);    // quad_perm xor1
                xp[mt * 4 + reg] = (t == 0) ? 0.f : (v + db1r);
            }
        if (t > 0 && w == 0 && l15 == 0) {
            #pragma unroll
            for (int mt = 0; mt < 2; mt++)
                #pragma unroll
                for (int reg = 0; reg < 4; reg++)
                    outb[mt * 16 + quad * 4 + reg][t] = xp[mt * 4 + reg];
        }

        // gates -> h_{t+1} into planes[nxt]; hold stays fp32
        if (t < 49) {
            #pragma unroll
            for (int mt = 0; mt < 2; mt++) {
                #pragma unroll
                for (int reg = 0; reg < 4; reg++) {
                    const int b = mt * 16 + quad * 4 + reg;
                    const float xpv = xp[mt * 4 + reg];
                    float gr  = fmaf(xpv, wihc0, acc[mt][0][reg] + bs_r);
                    float gz  = fmaf(xpv, wihc1, acc[mt][1][reg] + bs_z);
                    float ghn = acc[mt][2][reg] + bhh_n;
                    float gxn = fmaf(xpv, wihc2, bih_n);
                    float rg = fast_sigmoid(gr);
                    float zg = fast_sigmoid(gz);
                    float ng = fast_tanh(fmaf(rg, ghn, gxn));
                    const float hn = fmaf(zg, hold[mt * 4 + reg] - ng, ng);
                    hold[mt * 4 + reg] = hn;
                    h16[nxt][b][jcol] = (_Float16)hn;
                }
            }
        }
        __syncthreads();   // planes[nxt] complete; outb[t] visible
    }

    // coalesced output write: [32 rows][50 cols], col 0 = 0
    for (int e = tid; e < 32 * 50; e += NTH) {
        const int b = e / 50;
        const int t = e - b * 50;
        out[(size_t)b0 * 50 + e] = outb[b][t];
    }
}

// ---------------------------------------------------------------------------
extern "C" void kernel_launch(void* const* d_in, const int* in_sizes, int n_in,
                              void* d_out, int out_size, void* d_ws, size_t ws_size,
                              hipStream_t stream) {
    const float* x   = (const float*)d_in[0];
    const float* ew0 = (const float*)d_in[1];
    const float* eb0 = (const float*)d_in[2];
    const float* ew1 = (const float*)d_in[3];
    const float* eb1 = (const float*)d_in[4];
    const float* ew2 = (const float*)d_in[5];
    const float* eb2 = (const float*)d_in[6];
    const float* wih = (const float*)d_in[7];
    const float* whh = (const float*)d_in[8];
    const float* bih = (const float*)d_in[9];
    const float* bhh = (const float*)d_in[10];
    const float* dw0 = (const float*)d_in[11];
    const float* db0 = (const float*)d_in[12];
    const float* dw1 = (const float*)d_in[13];
    const float* db1 = (const float*)d_in[14];
    float* out = (float*)d_out;

    gru_fused_kernel<<<256, NTH, 0, stream>>>(
        x, ew0, eb0, ew1, eb1, ew2, eb2, wih, whh, bih, bhh,
        dw0, db0, dw1, db1, out);
}

// Round 13
// 201.384 us; speedup vs baseline: 1.2753x; 1.0461x over previous
//
#include <hip/hip_runtime.h>

#define NTH 256   // 4 waves; 16 rows/block; grid 512 -> 2 independent blocks/CU

typedef _Float16 half8 __attribute__((ext_vector_type(8)));
typedef __attribute__((ext_vector_type(4))) float floatx4;

__device__ __forceinline__ float fast_sigmoid(float x) {
    return __builtin_amdgcn_rcpf(1.f + __expf(-x));
}
__device__ __forceinline__ float fast_tanh(float x) {
    return fmaf(-2.f, __builtin_amdgcn_rcpf(__expf(2.f * x) + 1.f), 1.f);
}

// DPP add stage; 0x140,0x141,0x4E,0xB1 together = 16-lane sum broadcast
template<int CTRL>
__device__ __forceinline__ float dpp_add(float v) {
    int o = __builtin_amdgcn_update_dpp(0, __float_as_int(v), CTRL, 0xF, 0xF, true);
    return v + __int_as_float(o);
}

#define MFMA16 __builtin_amdgcn_mfma_f32_16x16x32_f16

// ---------------------------------------------------------------------------
// Encoder layer: [16,128] (LDS) @ W[128,128] + bias -> [16,128] (LDS)
// 256 threads: c = tid&127 (out col), g = tid>>7 (row group of 8)
// ---------------------------------------------------------------------------
template<bool RELU>
__device__ __forceinline__ void mlp_layer(const float (*in)[132],
                                          const float* __restrict__ W,
                                          const float* __restrict__ bias,
                                          float (*outl)[132], int c, int g) {
    float acc[8];
    #pragma unroll
    for (int i = 0; i < 8; i++) acc[i] = 0.f;
    for (int k = 0; k < 128; k += 4) {
        float w0 = W[(k + 0) * 128 + c];
        float w1 = W[(k + 1) * 128 + c];
        float w2 = W[(k + 2) * 128 + c];
        float w3 = W[(k + 3) * 128 + c];
        #pragma unroll
        for (int i = 0; i < 8; i++) {
            const float4 xv = *(const float4*)&in[g * 8 + i][k];
            acc[i] = fmaf(xv.x, w0, fmaf(xv.y, w1, fmaf(xv.z, w2, fmaf(xv.w, w3, acc[i]))));
        }
    }
    const float bv = bias[c];
    #pragma unroll
    for (int i = 0; i < 8; i++) {
        float v = acc[i] + bv;
        outl[g * 8 + i][c] = RELU ? fmaxf(v, 0.f) : v;
    }
}

// ---------------------------------------------------------------------------
// Fused encoder + 50-iter GRU (single-pass f16 MFMA) + per-wave decoder.
// 16 rows/block, 4 waves; wave w owns gate cols {g*128 + w*32 + nt*16 + l15}.
// Two blocks per CU with independent barriers -> MFMA/VALU phases of the two
// co-resident waves per SIMD overlap (m114 co-scheduling).
// ---------------------------------------------------------------------------
__global__ __launch_bounds__(NTH, 2)
void gru_fused_kernel(const float* __restrict__ x,
                      const float* __restrict__ ew0, const float* __restrict__ eb0,
                      const float* __restrict__ ew1, const float* __restrict__ eb1,
                      const float* __restrict__ ew2, const float* __restrict__ eb2,
                      const float* __restrict__ w_ih, const float* __restrict__ w_hh,
                      const float* __restrict__ b_ih, const float* __restrict__ b_hh,
                      const float* __restrict__ dw0, const float* __restrict__ db0,
                      const float* __restrict__ dw1, const float* __restrict__ db1,
                      float* __restrict__ out) {
    __shared__ float hA[16][132];                        // encoder staging
    __shared__ float smemB[16 * 132];                    // encoder ping buffer
    __shared__ __align__(16) _Float16 h16[2][16][136];   // f16 h planes (dbuf)
    __shared__ float outb[16][52];

    const int tid  = threadIdx.x;
    const int b0   = blockIdx.x * 16;
    const int lane = tid & 63;
    const int w    = tid >> 6;     // wave 0..3
    const int quad = lane >> 4;
    const int l15  = lane & 15;

    // ---------------- encoder: x -> hA ----------------
    {
        const int c = tid & 127;
        const int g = tid >> 7;    // 0..1, 8 rows each
        float acc[8];
        #pragma unroll
        for (int i = 0; i < 8; i++) acc[i] = 0.f;
        for (int k = 0; k < 256; k += 4) {
            float w0 = ew0[(k + 0) * 128 + c];
            float w1 = ew0[(k + 1) * 128 + c];
            float w2 = ew0[(k + 2) * 128 + c];
            float w3 = ew0[(k + 3) * 128 + c];
            #pragma unroll
            for (int i = 0; i < 8; i++) {
                const float4 xv = *(const float4*)(x + (size_t)(b0 + g * 8 + i) * 256 + k);
                acc[i] = fmaf(xv.x, w0, fmaf(xv.y, w1, fmaf(xv.z, w2, fmaf(xv.w, w3, acc[i]))));
            }
        }
        float bv = eb0[c];
        #pragma unroll
        for (int i = 0; i < 8; i++) hA[g * 8 + i][c] = fmaxf(acc[i] + bv, 0.f);
        __syncthreads();
        mlp_layer<true>(hA, ew1, eb1, (float(*)[132])smemB, c, g);
        __syncthreads();
        mlp_layer<false>((float(*)[132])smemB, ew2, eb2, hA, c, g);
        __syncthreads();
    }

    // ---------------- persistent register weights (f16) ----------------
    // wave w covers gate cols n = g*128 + w*32 + nt*16 + l15, nt in {0,1}
    half8 wb16[3][2][4];
    #pragma unroll
    for (int g = 0; g < 3; g++)
        #pragma unroll
        for (int nt = 0; nt < 2; nt++) {
            const float* wrow = w_hh + (g * 128 + w * 32 + nt * 16 + l15) * 128;
            #pragma unroll
            for (int kt = 0; kt < 4; kt++) {
                const int kb = kt * 32 + quad * 8;
                half8 hv;
                #pragma unroll
                for (int e = 0; e < 8; e++) hv[e] = (_Float16)wrow[kb + e];
                wb16[g][nt][kt] = hv;
            }
        }
    half8 dw16[4];
    #pragma unroll
    for (int kt = 0; kt < 4; kt++) {
        half8 hv;
        #pragma unroll
        for (int e = 0; e < 8; e++)
            hv[e] = (_Float16)dw0[(kt * 32 + quad * 8 + e) * 16 + l15];
        dw16[kt] = hv;
    }
    // gate constants per nt
    float wihc[3][2], bsum[2][2], bih_n[2], bhh_n[2];
    #pragma unroll
    for (int nt = 0; nt < 2; nt++) {
        const int jc = w * 32 + nt * 16 + l15;
        wihc[0][nt] = w_ih[jc];
        wihc[1][nt] = w_ih[128 + jc];
        wihc[2][nt] = w_ih[256 + jc];
        bsum[0][nt] = b_ih[jc] + b_hh[jc];
        bsum[1][nt] = b_ih[128 + jc] + b_hh[128 + jc];
        bih_n[nt]   = b_ih[256 + jc];
        bhh_n[nt]   = b_hh[256 + jc];
    }
    const float db0r = db0[l15];
    const float dw1r = dw1[l15];
    const float db1r = db1[0];

    // ---------------- init planes[0] + lane-private fp32 h ----------------
    for (int i = tid; i < 16 * 128; i += NTH) {
        const int b = i >> 7, j = i & 127;
        h16[0][b][j] = (_Float16)hA[b][j];
    }
    if (tid < 16) outb[tid][0] = 0.f;
    float hold[8];   // [nt*4+reg] = h at (row quad*4+reg, col w*32+nt*16+l15)
    #pragma unroll
    for (int nt = 0; nt < 2; nt++)
        #pragma unroll
        for (int reg = 0; reg < 4; reg++)
            hold[nt * 4 + reg] = hA[quad * 4 + reg][w * 32 + nt * 16 + l15];
    __syncthreads();

    // ---------------- 50 iterations: dec(h_t) -> out[t]; gates -> h_{t+1} ---
    for (int t = 0; t <= 49; t++) {
        const int cur = t & 1, nxt = cur ^ 1;

        // A-frags (4 b128; single drain)
        half8 ah[4];
        #pragma unroll
        for (int kt = 0; kt < 4; kt++)
            ah[kt] = *(const half8*)&h16[cur][l15][kt * 32 + quad * 8];

        // decoder (single pass): dacc ready early
        floatx4 dacc = (floatx4){0.f, 0.f, 0.f, 0.f};
        #pragma unroll
        for (int kt = 0; kt < 4; kt++)
            dacc = MFMA16(ah[kt], dw16[kt], dacc, 0, 0, 0);

        // GRU MFMAs (single pass f16): acc[gate][nt]
        floatx4 acc[3][2];
        #pragma unroll
        for (int g = 0; g < 3; g++)
            #pragma unroll
            for (int nt = 0; nt < 2; nt++) acc[g][nt] = (floatx4){0.f, 0.f, 0.f, 0.f};
        #pragma unroll
        for (int kt = 0; kt < 4; kt++)
            #pragma unroll
            for (int g = 0; g < 3; g++) {
                acc[g][0] = MFMA16(ah[kt], wb16[g][0][kt], acc[g][0], 0, 0, 0);
                acc[g][1] = MFMA16(ah[kt], wb16[g][1][kt], acc[g][1], 0, 0, 0);
            }

        // decoder reduce via DPP (16-lane sum within quad-row, broadcast)
        float xp[4];
        #pragma unroll
        for (int reg = 0; reg < 4; reg++) {
            float v = fmaxf(dacc[reg] + db0r, 0.f) * dw1r;
            v = dpp_add<0x140>(v);   // row_mirror
            v = dpp_add<0x141>(v);   // row_half_mirror
            v = dpp_add<0x4E>(v);    // quad_perm xor2
            v = dpp_add<0xB1>(v);    // quad_perm xor1
            xp[reg] = (t == 0) ? 0.f : (v + db1r);
        }
        if (t > 0 && w == 0 && l15 == 0) {
            #pragma unroll
            for (int reg = 0; reg < 4; reg++)
                outb[quad * 4 + reg][t] = xp[reg];
        }

        // gates -> h_{t+1} into planes[nxt]; hold stays fp32
        if (t < 49) {
            #pragma unroll
            for (int nt = 0; nt < 2; nt++) {
                #pragma unroll
                for (int reg = 0; reg < 4; reg++) {
                    const int b = quad * 4 + reg;
                    const float xpv = xp[reg];
                    float gr  = fmaf(xpv, wihc[0][nt], acc[0][nt][reg] + bsum[0][nt]);
                    float gz  = fmaf(xpv, wihc[1][nt], acc[1][nt][reg] + bsum[1][nt]);
                    float ghn = acc[2][nt][reg] + bhh_n[nt];
                    float gxn = fmaf(xpv, wihc[2][nt], bih_n[nt]);
                    float rg = fast_sigmoid(gr);
                    float zg = fast_sigmoid(gz);
                    float ng = fast_tanh(fmaf(rg, ghn, gxn));
                    const float hn = fmaf(zg, hold[nt * 4 + reg] - ng, ng);
                    hold[nt * 4 + reg] = hn;
                    h16[nxt][b][w * 32 + nt * 16 + l15] = (_Float16)hn;
                }
            }
        }
        __syncthreads();   // planes[nxt] complete; outb[t] visible
    }

    // coalesced output write: [16 rows][50 cols], col 0 = 0
    for (int e = tid; e < 16 * 50; e += NTH) {
        const int b = e / 50;
        const int t = e - b * 50;
        out[(size_t)b0 * 50 + e] = outb[b][t];
    }
}

// ---------------------------------------------------------------------------
extern "C" void kernel_launch(void* const* d_in, const int* in_sizes, int n_in,
                              void* d_out, int out_size, void* d_ws, size_t ws_size,
                              hipStream_t stream) {
    const float* x   = (const float*)d_in[0];
    const float* ew0 = (const float*)d_in[1];
    const float* eb0 = (const float*)d_in[2];
    const float* ew1 = (const float*)d_in[3];
    const float* eb1 = (const float*)d_in[4];
    const float* ew2 = (const float*)d_in[5];
    const float* eb2 = (const float*)d_in[6];
    const float* wih = (const float*)d_in[7];
    const float* whh = (const float*)d_in[8];
    const float* bih = (const float*)d_in[9];
    const float* bhh = (const float*)d_in[10];
    const float* dw0 = (const float*)d_in[11];
    const float* db0 = (const float*)d_in[12];
    const float* dw1 = (const float*)d_in[13];
    const float* db1 = (const float*)d_in[14];
    float* out = (float*)d_out;

    gru_fused_kernel<<<512, NTH, 0, stream>>>(
        x, ew0, eb0, ew1, eb1, ew2, eb2, wih, whh, bih, bhh,
        dw0, db0, dw1, db1, out);
}